// Round 5
// baseline (69.126 us; speedup 1.0000x reference)
//
#include <hip/hip_runtime.h>
#include <hip/hip_bf16.h>

typedef int v4i __attribute__((ext_vector_type(4)));
typedef float v4f __attribute__((ext_vector_type(4)));

// Padded quantized activations: qp[n][hp][wp][c], hp,wp in [0,114), c in [0,64)
#define QP_N 32
#define QP_HP 114
#define QP_WP 114
#define QP_C 64
#define QP_ROW (QP_WP * QP_C)                            // 7296 B per padded row
#define QP_BYTES ((size_t)QP_N * QP_HP * QP_WP * QP_C)   // 26,615,808

#define QBLOCKS (QP_N * QP_HP)      // 3648 quantize blocks
#define PBLOCKS 9                   // prepack blocks folded into same launch

#define W_LDS 36864                 // 36 frags * 1024 B
#define A_ROWS 6
#define A_LDS (A_ROWS * QP_ROW)     // 43776
// total LDS/block = 80640 B -> 2 blocks/CU (161280 <= 163840)

// ---------------------------------------------------------------------------
// Kernel 1: quantize + NCHW -> padded NHWC int8 transpose, with border zeroing.
// Blocks [0, 3648): block (n, hp). hp==0/113 -> zero row. Else transpose row
// h=hp-1 through LDS and zero the wp=0 / wp=113 columns. x loads nontemporal
// (read-once; keep L2 for qp). qp stores cached (conv re-reads).
// Blocks [3648, 3657): weight prepack into MFMA B-fragment layout.
//   wb[frag][lane][16B], frag = (kh*3+kw)*4 + g.
//   B-frag (K=ci x N=co): lane l holds B[k=(l>>4)*16+j][n = l&15], j=0..15.
//   co = g*16 + (l&15), ci = (l>>4)*16 + j.  qw arrives widened to int32.
// ---------------------------------------------------------------------------
__global__ __launch_bounds__(256) void quantize_kernel(const float* __restrict__ x,
                                                       signed char* __restrict__ qp,
                                                       const int* __restrict__ qw,
                                                       signed char* __restrict__ wb) {
    int t = threadIdx.x;

    if (blockIdx.x >= QBLOCKS) {
        // ---- prepack path ----
        int idx = (blockIdx.x - QBLOCKS) * 256 + t;
        if (idx >= 36 * 64) return;
        int lane = idx & 63;
        int frag = idx >> 6;             // 0..35
        int g = frag & 3;
        int tap = frag >> 2;             // kh*3+kw
        int kh = tap / 3;
        int kw = tap - kh * 3;
        int co = g * 16 + (lane & 15);
        int cibase = (lane >> 4) * 16;
        int dwv[4];
#pragma unroll
        for (int d = 0; d < 4; ++d) {
            int acc = 0;
#pragma unroll
            for (int b = 0; b < 4; ++b) {
                int ci = cibase + d * 4 + b;
                int v = qw[((co * 64 + ci) * 3 + kh) * 3 + kw];
                acc |= (v & 0xff) << (8 * b);
            }
            dwv[d] = acc;
        }
        *reinterpret_cast<int4*>(wb + (size_t)idx * 16) = make_int4(dwv[0], dwv[1], dwv[2], dwv[3]);
        return;
    }

    int nb = blockIdx.x;            // 0..3647
    int n = nb / QP_HP;
    int hp = nb - n * QP_HP;
    signed char* rowbase = qp + ((size_t)n * QP_HP + hp) * QP_ROW;

    if (hp == 0 || hp == QP_HP - 1) {
        // zero the whole padded row: 114*64 = 7296 B = 228 * 32B
        if (t < 228) {
            int4 z = make_int4(0, 0, 0, 0);
            int4* dst = reinterpret_cast<int4*>(rowbase + t * 32);
            dst[0] = z;
            dst[1] = z;
        }
        return;
    }

    int h = hp - 1;
    __shared__ float lds[64][112];

    const float* xp = x + (size_t)n * 64 * 12544 + h * 112;  // x[n][c][h][w], c-plane stride 12544
#pragma unroll
    for (int j = 0; j < 7; ++j) {
        int fidx = j * 256 + t;      // 1792 float4 chunks total (64 rows * 28)
        int c = fidx / 28;
        int f = fidx - c * 28;
        v4f v = __builtin_nontemporal_load(
            reinterpret_cast<const v4f*>(xp + (size_t)c * 12544 + f * 4));
        *reinterpret_cast<v4f*>(&lds[c][f * 4]) = v;
    }
    __syncthreads();

    if (t < 224) {
        int w = t >> 1;              // 0..111
        int ch = (t & 1) * 32;       // channel half: 0 or 32
        int dw[8];
#pragma unroll
        for (int q = 0; q < 8; ++q) {
            int d = 0;
#pragma unroll
            for (int b = 0; b < 4; ++b) {
                float v = lds[ch + q * 4 + b][w];
                float s = rintf(v * 20.0f);                 // round-half-to-even, matches jnp.round
                s = fminf(127.0f, fmaxf(-128.0f, s));
                int iv = (int)s;
                d |= (iv & 0xff) << (8 * b);
            }
            dw[q] = d;
        }
        int4* dst = reinterpret_cast<int4*>(rowbase + (size_t)(w + 1) * QP_C + ch);
        dst[0] = make_int4(dw[0], dw[1], dw[2], dw[3]);
        dst[1] = make_int4(dw[4], dw[5], dw[6], dw[7]);
    } else if (t < 232) {
        // zero border columns wp=0 and wp=113 (64 B each = 4 int4 each)
        int i = t - 224;
        int col = (i >> 2) ? (QP_WP - 1) : 0;
        int part = i & 3;
        *reinterpret_cast<int4*>(rowbase + (size_t)col * QP_C + part * 16) = make_int4(0, 0, 0, 0);
    }
}

// ---------------------------------------------------------------------------
// Kernel 2: implicit-GEMM conv, A = activations (M=16 px), B = weights (N=16 co).
// 512-thr blocks (8 waves = 4 output rows x 2 halves) for one image n.
// Block stages into LDS: 36 KB weights (linear) + 6 padded qp rows (43.8 KB,
// slot-swizzled). Inner loop is pure LDS + MFMA.
// A-tile swizzle: LDS[r][col][slot] holds QP[r][col][slot ^ ((col>>1)&3)]
// (16B slots, XOR involution; makes ds_write_b128 staging AND ds_read_b128
// fragment reads 2-way bank aliasing = free).
//   A-frag (pb,kh,kw): lane l: col = w0+pb*16+kw+(l&15), q=(l>>4):
//     atile[(hh+kh)*7296 + col*64 + (q ^ ((col>>1)&3))*16]   (pb*16, w0 don't
//     touch col bits 1..2 -> slot precomputable per kw)
//   D-frag (pb,g): co = g*16 + (l&15), pixels (l>>4)*4..+3 -> NT float4 stores
// ---------------------------------------------------------------------------
template <int NPB>
__device__ __forceinline__ void conv_tile(const signed char* arows,   // atile + hh*QP_ROW
                                          const int* aoff,            // [3] per-kw lane offsets
                                          const signed char* wl,
                                          const int* __restrict__ bias,
                                          const float* __restrict__ deq,
                                          float* __restrict__ outp,
                                          int lane) {
    v4i acc[NPB][4];
#pragma unroll
    for (int pb = 0; pb < NPB; ++pb)
#pragma unroll
        for (int g = 0; g < 4; ++g)
            acc[pb][g] = (v4i){0, 0, 0, 0};

#pragma unroll
    for (int kh = 0; kh < 3; ++kh) {
        const signed char* arow = arows + (size_t)kh * QP_ROW;
#pragma unroll
        for (int kw = 0; kw < 3; ++kw) {
            v4i w0f = *reinterpret_cast<const v4i*>(wl + (size_t)(((kh * 3 + kw) * 4 + 0)) * 1024);
            v4i w1f = *reinterpret_cast<const v4i*>(wl + (size_t)(((kh * 3 + kw) * 4 + 1)) * 1024);
            v4i w2f = *reinterpret_cast<const v4i*>(wl + (size_t)(((kh * 3 + kw) * 4 + 2)) * 1024);
            v4i w3f = *reinterpret_cast<const v4i*>(wl + (size_t)(((kh * 3 + kw) * 4 + 3)) * 1024);
            const signed char* abase = arow + aoff[kw];
#pragma unroll
            for (int pb = 0; pb < NPB; ++pb) {
                v4i af = *reinterpret_cast<const v4i*>(abase + pb * 1024);
                acc[pb][0] = __builtin_amdgcn_mfma_i32_16x16x64_i8(af, w0f, acc[pb][0], 0, 0, 0);
                acc[pb][1] = __builtin_amdgcn_mfma_i32_16x16x64_i8(af, w1f, acc[pb][1], 0, 0, 0);
                acc[pb][2] = __builtin_amdgcn_mfma_i32_16x16x64_i8(af, w2f, acc[pb][2], 0, 0, 0);
                acc[pb][3] = __builtin_amdgcn_mfma_i32_16x16x64_i8(af, w3f, acc[pb][3], 0, 0, 0);
            }
        }
    }

    int cbase = lane & 15;           // co within group
    int pq = (lane >> 4) * 4;        // pixel quad start within 16-px block
#pragma unroll
    for (int g = 0; g < 4; ++g) {
        int co = g * 16 + cbase;
        int bv = bias[co];
        float dv = deq[co];
        float* orow = outp + (size_t)co * 12544 + pq;
#pragma unroll
        for (int pb = 0; pb < NPB; ++pb) {
            v4f v;
            v.x = (float)(acc[pb][g][0] + bv) * dv;
            v.y = (float)(acc[pb][g][1] + bv) * dv;
            v.z = (float)(acc[pb][g][2] + bv) * dv;
            v.w = (float)(acc[pb][g][3] + bv) * dv;
            __builtin_nontemporal_store(v, reinterpret_cast<v4f*>(orow + pb * 16));
        }
    }
}

__global__ __launch_bounds__(512) void conv_kernel(const signed char* __restrict__ qp,
                                                   const signed char* __restrict__ wb,
                                                   const int* __restrict__ bias,
                                                   const float* __restrict__ deq,
                                                   float* __restrict__ out) {
    __shared__ alignas(16) signed char lds[W_LDS + A_LDS];   // 80640 B
    signed char* wlds = lds;
    signed char* atile = lds + W_LDS;

    int t = threadIdx.x;
    int bid = blockIdx.x;            // 0..895
    int n = bid / 28;
    int rb = bid - n * 28;
    int h0 = rb * 4;                 // output rows h0..h0+3; padded rows h0..h0+5

    // stage weights: 2304 x 16B, linear
#pragma unroll
    for (int i = 0; i < 5; ++i) {
        int idx = i * 512 + t;
        if (idx < 2304) {
            *reinterpret_cast<int4*>(wlds + (size_t)idx * 16) =
                *reinterpret_cast<const int4*>(wb + (size_t)idx * 16);
        }
    }
    // stage activations: 6 rows x 456 x 16B = 2736 chunks, swizzled dest
    const signed char* qbase = qp + ((size_t)(n * QP_HP + h0)) * QP_ROW;
#pragma unroll
    for (int i = 0; i < 6; ++i) {
        int idx = i * 512 + t;
        if (idx < A_ROWS * 456) {
            int r = idx / 456;
            int li = idx - r * 456;
            int col = li >> 2;
            int q = li & 3;
            int4 v = *reinterpret_cast<const int4*>(qbase + (size_t)r * QP_ROW + (size_t)li * 16);
            int slot = q ^ ((col >> 1) & 3);
            *reinterpret_cast<int4*>(atile + (size_t)r * QP_ROW + col * 64 + slot * 16) = v;
        }
    }
    __syncthreads();

    int wave = t >> 6;
    int lane = t & 63;
    int hh = wave >> 1;              // 0..3
    int half = wave & 1;
    int w0 = half ? 64 : 0;
    int h = h0 + hh;

    int wlane = lane & 15;
    int q = lane >> 4;
    int aoff[3];
#pragma unroll
    for (int kw = 0; kw < 3; ++kw) {
        int colb = w0 + kw + wlane;
        int slot = q ^ ((colb >> 1) & 3);
        aoff[kw] = colb * 64 + slot * 16;
    }

    const signed char* arows = atile + (size_t)hh * QP_ROW;
    const signed char* wl = wlds + lane * 16;     // B-frag f at wl + f*1024
    float* outp = out + (size_t)n * 64 * 12544 + h * 112 + w0;

    if (half == 0)
        conv_tile<4>(arows, aoff, wl, bias, deq, outp, lane);
    else
        conv_tile<3>(arows, aoff, wl, bias, deq, outp, lane);
}

extern "C" void kernel_launch(void* const* d_in, const int* in_sizes, int n_in,
                              void* d_out, int out_size, void* d_ws, size_t ws_size,
                              hipStream_t stream) {
    const float* x   = (const float*)d_in[0];
    const int*   qw  = (const int*)d_in[1];    // int8 values widened to int32
    const int*   bias = (const int*)d_in[2];
    const float* deq = (const float*)d_in[3];
    float* out = (float*)d_out;

    signed char* qp = (signed char*)d_ws;
    signed char* wb = qp + QP_BYTES;

    quantize_kernel<<<QBLOCKS + PBLOCKS, 256, 0, stream>>>(x, qp, qw, wb);
    conv_kernel<<<896, 512, 0, stream>>>(qp, wb, bias, deq, out);
}